// Round 2
// baseline (181.634 us; speedup 1.0000x reference)
//
#include <hip/hip_runtime.h>
#include <hip/hip_bf16.h>

// MaskedContrastiveLoss: loss = 0.5*[mean_i(rowLSE_i - pos_i) + mean_j(colLSE_j - pos_j)]
// logits = (A @ B^T) * (1/0.07), A,B: [256, 65536] fp32 L2-normalized rows.
//
// R2: latency-bound fix. 64x64 tiles x C=64 K-chunks -> grid 1024 (4 blk/CU,
// 16 waves/CU), double-buffered LDS with ONE barrier/stage so global loads
// stay in flight through the MFMA phase, XCD-swizzled block mapping so tile
// redundancy is served from one XCD's L2, float4 reduce.

#define D_DIM 65536
#define B_DIM 256
#define LDK 72  // padded LDS row stride (shorts): 144 B -> no 4-way+ conflicts

constexpr float TEMP = 1.0f / 0.07f;

typedef short short8 __attribute__((ext_vector_type(8)));
typedef float floatx4 __attribute__((ext_vector_type(4)));

__device__ inline unsigned short f2bf(float f) {
  unsigned u = __builtin_bit_cast(unsigned, f);
  unsigned rounding = 0x7fffu + ((u >> 16) & 1u);  // RNE (finite inputs)
  return (unsigned short)((u + rounding) >> 16);
}

__device__ inline void st_bf16x4(unsigned short* dst, float4 v) {
  uint2 u;
  u.x = (unsigned)f2bf(v.x) | ((unsigned)f2bf(v.y) << 16);
  u.y = (unsigned)f2bf(v.z) | ((unsigned)f2bf(v.w) << 16);
  *(uint2*)dst = u;
}

// grid = 16 * C blocks, 256 threads (4 waves).
// chunk = bid & (C-1)  -> consecutive chunks round-robin XCDs;
// tile  = bid >> cshift -> the 16 blocks sharing chunk data sit on ONE XCD.
__global__ __launch_bounds__(256, 4) void gemm_splitk(
    const float* __restrict__ A, const float* __restrict__ Bm,
    float* __restrict__ partials, int Kc, int cshift) {
  const int bid = blockIdx.x;
  const int chunk = bid & ((1 << cshift) - 1);
  const int tile = bid >> cshift;
  const int mt = (tile & 3) * 64;
  const int nt = (tile >> 2) * 64;
  const size_t k0 = (size_t)chunk * (size_t)Kc;

  __shared__ unsigned short As[2][64][LDK];
  __shared__ unsigned short Bs[2][64][LDK];

  const int t = threadIdx.x;
  const int lane = t & 63;
  const int w = t >> 6;        // wave 0..3
  const int wm = w * 16;       // wave's 16-row strip of the 64x64 tile
  const int lane15 = lane & 15;
  const int laneq = lane >> 4;

  // staging: 16 threads cover one row's 64 floats (16 x float4), 16 rows/pass
  const int lr = t >> 4;           // 0..15
  const int lc = (t & 15) * 4;     // col within BK=64

  const float* Abase = A + (size_t)(mt + lr) * D_DIM + k0 + lc;
  const float* Bbase = Bm + (size_t)(nt + lr) * D_DIM + k0 + lc;

  floatx4 acc[4];
#pragma unroll
  for (int nb = 0; nb < 4; ++nb) acc[nb] = (floatx4)0.f;

  float4 ra[4], rb[4];
  const int nst = Kc >> 6;  // stages of BK=64

  // prefetch stage 0
#pragma unroll
  for (int p = 0; p < 4; ++p) {
    ra[p] = *(const float4*)(Abase + (size_t)p * 16 * D_DIM);
    rb[p] = *(const float4*)(Bbase + (size_t)p * 16 * D_DIM);
  }

  for (int s = 0; s < nst; ++s) {
    const int buf = s & 1;
    // convert + store stage s (drains the in-flight loads)
#pragma unroll
    for (int p = 0; p < 4; ++p) {
      st_bf16x4(&As[buf][lr + p * 16][lc], ra[p]);
      st_bf16x4(&Bs[buf][lr + p * 16][lc], rb[p]);
    }
    __syncthreads();  // single barrier per stage (dbuf makes this safe)

    // issue next stage's loads immediately -> in flight through MFMA phase
    if (s + 1 < nst) {
      const float* Ap = Abase + (size_t)(s + 1) * 64;
      const float* Bp = Bbase + (size_t)(s + 1) * 64;
#pragma unroll
      for (int p = 0; p < 4; ++p) {
        ra[p] = *(const float4*)(Ap + (size_t)p * 16 * D_DIM);
        rb[p] = *(const float4*)(Bp + (size_t)p * 16 * D_DIM);
      }
    }

    // MFMA over BK=64: 2 K-steps of 32
#pragma unroll
    for (int ks = 0; ks < 64; ks += 32) {
      const int ko = ks + laneq * 8;
      short8 af = *(const short8*)&As[buf][wm + lane15][ko];
      short8 bf[4];
#pragma unroll
      for (int nb = 0; nb < 4; ++nb)
        bf[nb] = *(const short8*)&Bs[buf][nb * 16 + lane15][ko];
#pragma unroll
      for (int nb = 0; nb < 4; ++nb)
        acc[nb] = __builtin_amdgcn_mfma_f32_16x16x32_bf16(af, bf[nb], acc[nb], 0, 0, 0);
    }
  }

  // epilogue: C/D layout col=lane&15, row=(lane>>4)*4+r
  float* outp = partials + (size_t)chunk * (B_DIM * B_DIM);
  const int gi0 = mt + wm + laneq * 4;
#pragma unroll
  for (int nb = 0; nb < 4; ++nb) {
    const int gj = nt + nb * 16 + lane15;
#pragma unroll
    for (int r = 0; r < 4; ++r)
      outp[(size_t)(gi0 + r) * B_DIM + gj] = acc[nb][r];
  }
}

// block i: sum C partial rows (float4, parallel over 4 C-slices), logits row,
// rowLSE_i, pos_i -> atomicAdd (rowLSE_i - 2*pos_i)*0.5/256.
__global__ void reduce_rows(const float* __restrict__ partials,
                            float* __restrict__ logits,
                            float* __restrict__ out, int C) {
  const int i = blockIdx.x;
  const int t = threadIdx.x;
  const int slice = t >> 6;        // 0..3
  const int col4 = (t & 63) * 4;   // 0,4,...,252

  const int cper = C >> 2;  // C is a power of two >= 4
  const float* p = partials + (size_t)(slice * cper) * (B_DIM * B_DIM) +
                   (size_t)i * B_DIM + col4;
  float4 s = make_float4(0.f, 0.f, 0.f, 0.f);
#pragma unroll 8
  for (int c = 0; c < cper; ++c) {
    float4 v = *(const float4*)(p + (size_t)c * (B_DIM * B_DIM));
    s.x += v.x; s.y += v.y; s.z += v.z; s.w += v.w;
  }
  __shared__ float sbuf[4][B_DIM];
  *(float4*)&sbuf[slice][col4] = s;
  __syncthreads();

  const int j = t;  // 0..255
  const float lg = (sbuf[0][j] + sbuf[1][j] + sbuf[2][j] + sbuf[3][j]) * TEMP;
  logits[i * B_DIM + j] = lg;

  __shared__ float posv;
  if (j == i) posv = lg;

  float e = expf(lg);  // |lg| <= 14.3 (Cauchy-Schwarz): no max-shift needed
#pragma unroll
  for (int off = 32; off > 0; off >>= 1) e += __shfl_down(e, off);
  __shared__ float wsum[4];
  if ((j & 63) == 0) wsum[j >> 6] = e;
  __syncthreads();
  if (j == 0) {
    const float tot = wsum[0] + wsum[1] + wsum[2] + wsum[3];
    atomicAdd(out, (logf(tot) - 2.f * posv) * (0.5f / 256.f));
  }
}

// block j: colLSE_j from logits -> atomicAdd colLSE_j*0.5/256.
__global__ void reduce_cols(const float* __restrict__ logits,
                            float* __restrict__ out) {
  const int j = blockIdx.x;
  const int i = threadIdx.x;
  float e = expf(logits[(size_t)i * B_DIM + j]);
#pragma unroll
  for (int off = 32; off > 0; off >>= 1) e += __shfl_down(e, off);
  __shared__ float wsum[4];
  if ((i & 63) == 0) wsum[i >> 6] = e;
  __syncthreads();
  if (i == 0) {
    const float tot = wsum[0] + wsum[1] + wsum[2] + wsum[3];
    atomicAdd(out, logf(tot) * (0.5f / 256.f));
  }
}

extern "C" void kernel_launch(void* const* d_in, const int* in_sizes, int n_in,
                              void* d_out, int out_size, void* d_ws, size_t ws_size,
                              hipStream_t stream) {
  (void)in_sizes; (void)n_in; (void)out_size;
  const float* A = (const float*)d_in[0];
  const float* Bm = (const float*)d_in[1];
  float* out = (float*)d_out;

  // ws layout: [logits: 256*256 f32][partials: C * 256*256 f32]
  const size_t per = (size_t)B_DIM * B_DIM * sizeof(float);  // 256 KB
  int C = 64;
  while (C > 4 && (size_t)(C + 1) * per > ws_size) C >>= 1;
  const int Kc = D_DIM / C;
  int cshift = 0;
  while ((1 << cshift) < C) ++cshift;

  float* logits = (float*)d_ws;
  float* partials = (float*)d_ws + (size_t)B_DIM * B_DIM;

  hipMemsetAsync(d_out, 0, sizeof(float), stream);
  gemm_splitk<<<16 * C, 256, 0, stream>>>(A, Bm, partials, Kc, cshift);
  reduce_rows<<<B_DIM, B_DIM, 0, stream>>>(partials, logits, out, C);
  reduce_cols<<<B_DIM, B_DIM, 0, stream>>>(logits, out);
}